// Round 2
// baseline (1004.219 us; speedup 1.0000x reference)
//
#include <hip/hip_runtime.h>
#include <cstdint>
#include <cstddef>

// GRU (reset_after) + dense(1)+sigmoid, masked by per-batch length t.
// ONE WAVE per sequence: 512 blocks x 64 threads. Zero barriers.
// Lane j owns gate columns {j, 64+j, 128+j}: U-cols (3x64) + W-cols (3x24)
// pre-paired in VGPRs for v_pk_fma_f32 (2 fp32 FMA / instruction).
// h broadcast via same-wave LDS write->read (lgkmcnt only, no syncthreads).
// x staged in double-buffered LDS chunks of 64 steps, register-prefetched.
// Per-step output dot deferred one step; 6-level shfl_xor reduce interleaves
// with the next step's independent pk_fma stream.

typedef float v2f __attribute__((ext_vector_type(2)));

__device__ __forceinline__ void pkfma(v2f& acc, const v2f a, const v2f b) {
    // acc = a*b + acc (packed 2xfp32)
    asm("v_pk_fma_f32 %0, %1, %2, %0" : "+v"(acc) : "v"(a), "v"(b));
}

__global__ __launch_bounds__(64, 1) void gru_wave_kernel(
    const float* __restrict__ xg,      // (512,1024,24)
    const int*   __restrict__ tg,      // (512,)
    const float* __restrict__ Wg,      // (24,192)
    const float* __restrict__ Ug,      // (64,192)
    const float* __restrict__ bg,      // (2,192)
    const float* __restrict__ Wdg,     // (64,1)
    const float* __restrict__ bdg,     // (1,)
    float*       __restrict__ outg)    // (512,1024)
{
    const int b = blockIdx.x;
    const int j = threadIdx.x;          // lane 0..63

    __shared__ __align__(16) float xbuf[2][1536];   // 2 x (64 steps x 24 floats)
    __shared__ __align__(16) float h_lds[64];

    const int   t    = tg[b];
    float*      outb = outg + (size_t)b * 1024;
    const float bdv  = bdg[0];

    if (t <= 0) {
        const float fill = 1.f / (1.f + __expf(-bdv));
        for (int i = j; i < 1024; i += 64) outb[i] = fill;
        return;
    }

    // ---- weight preload: pre-paired along the reduction dim for pk_fma ----
    v2f Uz[32], Ur[32], Uc[32];
    #pragma unroll
    for (int k = 0; k < 32; ++k) {
        const float* r0 = Ug + (2 * k)     * 192;
        const float* r1 = Ug + (2 * k + 1) * 192;
        Uz[k] = (v2f){ r0[j],       r1[j]       };
        Ur[k] = (v2f){ r0[64 + j],  r1[64 + j]  };
        Uc[k] = (v2f){ r0[128 + j], r1[128 + j] };
    }
    v2f Wz[12], Wr[12], Wc[12];
    #pragma unroll
    for (int d = 0; d < 12; ++d) {
        const float* r0 = Wg + (2 * d)     * 192;
        const float* r1 = Wg + (2 * d + 1) * 192;
        Wz[d] = (v2f){ r0[j],       r1[j]       };
        Wr[d] = (v2f){ r0[64 + j],  r1[64 + j]  };
        Wc[d] = (v2f){ r0[128 + j], r1[128 + j] };
    }
    const float b0z = bg[j],        b0r = bg[64 + j],        b0c = bg[128 + j];
    const float b1z = bg[192 + j],  b1r = bg[256 + j],       b1c = bg[320 + j];
    const float wdj = Wdg[j];

    const float* xb = xg + (size_t)b * 24576;   // 1024*24

    // ---- prologue: stage chunk 0, prefetch chunk 1, zero h ----
    float4 pf[6];
    {
        const float4* src = (const float4*)xb;
        #pragma unroll
        for (int i = 0; i < 6; ++i) pf[i] = src[i * 64 + j];
        float4* dst = (float4*)xbuf[0];
        #pragma unroll
        for (int i = 0; i < 6; ++i) dst[i * 64 + j] = pf[i];
        if (64 < t) {
            const float4* nsrc = (const float4*)(xb + 1536);
            #pragma unroll
            for (int i = 0; i < 6; ++i) pf[i] = nsrc[i * 64 + j];
        }
    }
    h_lds[j] = 0.f;

    float hold = 0.f;   // lane j's own h_j
    float p    = 0.f;   // deferred output partial: h_j * wd_j

    for (int s = 0; s < t; ++s) {
        const int c   = s & 63;
        const int buf = (s >> 6) & 1;

        // ---- chunk boundary: commit prefetched x, start next prefetch ----
        if (c == 0 && s > 0) {
            float4* dst = (float4*)xbuf[buf];
            #pragma unroll
            for (int i = 0; i < 6; ++i) dst[i * 64 + j] = pf[i];
            const int nc = (s >> 6) + 1;
            if (nc * 64 < t) {
                const float4* nsrc = (const float4*)(xb + nc * 1536);
                #pragma unroll
                for (int i = 0; i < 6; ++i) pf[i] = nsrc[i * 64 + j];
            }
        }

        // ---- issue broadcast reads (h round-trip is the chain head) ----
        float4 h4[16];
        #pragma unroll
        for (int i = 0; i < 16; ++i) h4[i] = ((const float4*)h_lds)[i];
        float4 x4[6];
        {
            const float4* xr = (const float4*)(xbuf[buf] + c * 24);
            #pragma unroll
            for (int i = 0; i < 6; ++i) x4[i] = xr[i];
        }

        // ---- deferred output reduce for step s-1 (off the h-chain; its
        //      shfl latency interleaves with the pk_fma stream below) ----
        if (s > 0) {
            float tot = p;
            #pragma unroll
            for (int m = 1; m < 64; m <<= 1) tot += __shfl_xor(tot, m, 64);
            if (j == 0) outb[s - 1] = 1.f / (1.f + __expf(-(tot + bdv)));
        }

        // ---- packed matvecs: 96 + 36 pk_fma ----
        v2f za = (v2f){0.f, 0.f}, ra = za, ca = za;
        #pragma unroll
        for (int i = 0; i < 16; ++i) {
            const v2f hlo = (v2f){ h4[i].x, h4[i].y };
            const v2f hhi = (v2f){ h4[i].z, h4[i].w };
            pkfma(za, Uz[2 * i], hlo); pkfma(za, Uz[2 * i + 1], hhi);
            pkfma(ra, Ur[2 * i], hlo); pkfma(ra, Ur[2 * i + 1], hhi);
            pkfma(ca, Uc[2 * i], hlo); pkfma(ca, Uc[2 * i + 1], hhi);
        }
        v2f xza = (v2f){0.f, 0.f}, xra = xza, xca = xza;
        #pragma unroll
        for (int i = 0; i < 6; ++i) {
            const v2f xlo = (v2f){ x4[i].x, x4[i].y };
            const v2f xhi = (v2f){ x4[i].z, x4[i].w };
            pkfma(xza, Wz[2 * i], xlo); pkfma(xza, Wz[2 * i + 1], xhi);
            pkfma(xra, Wr[2 * i], xlo); pkfma(xra, Wr[2 * i + 1], xhi);
            pkfma(xca, Wc[2 * i], xlo); pkfma(xca, Wc[2 * i + 1], xhi);
        }

        // ---- gates + state update (per-lane, no cross-lane traffic) ----
        const float hz = za.x + za.y + b1z;
        const float hr = ra.x + ra.y + b1r;
        const float hc = ca.x + ca.y + b1c;
        const float xz = xza.x + xza.y + b0z;
        const float xr = xra.x + xra.y + b0r;
        const float xc = xca.x + xca.y + b0c;

        const float z  = 1.f / (1.f + __expf(-(xz + hz)));
        const float r  = 1.f / (1.f + __expf(-(xr + hr)));
        // tanh(y) = 1 - 2/(1+exp(2y))
        const float cg = 1.f - 2.f / (1.f + __expf(2.f * (xc + r * hc)));
        const float hn = z * hold + (1.f - z) * cg;

        hold = hn;
        h_lds[j] = hn;          // next step's broadcast source (same wave)
        p = hn * wdj;
    }

    // ---- final step's output + constant tail fill (h frozen for s >= t) ----
    float tot = p;
    #pragma unroll
    for (int m = 1; m < 64; m <<= 1) tot += __shfl_xor(tot, m, 64);
    const float o = 1.f / (1.f + __expf(-(tot + bdv)));
    for (int i = t - 1 + j; i < 1024; i += 64) outb[i] = o;
}

extern "C" void kernel_launch(void* const* d_in, const int* in_sizes, int n_in,
                              void* d_out, int out_size, void* d_ws, size_t ws_size,
                              hipStream_t stream) {
    (void)in_sizes; (void)n_in; (void)d_ws; (void)ws_size; (void)out_size;
    const float* x  = (const float*)d_in[0];
    const int*   t  = (const int*)d_in[1];
    const float* W  = (const float*)d_in[2];
    const float* U  = (const float*)d_in[3];
    const float* bb = (const float*)d_in[4];
    const float* Wd = (const float*)d_in[5];
    const float* bd = (const float*)d_in[6];
    float* out = (float*)d_out;

    hipLaunchKernelGGL(gru_wave_kernel, dim3(512), dim3(64), 0, stream,
                       x, t, W, U, bb, Wd, bd, out);
}